// Round 3
// baseline (508.730 us; speedup 1.0000x reference)
//
#include <hip/hip_runtime.h>
#include <cstdint>

// ---- problem constants (MoEFeedForward: N=4096, D=1024, F=2048, E=8, top-2) ----
#define N_TOK 4096
#define D_MODEL 1024
#define D_FF 2048
#define D_GU 4096          // 2*D_FF: gate_up row space in w_gate_up
#define N_EXP 8

typedef __bf16 bf16;
typedef __bf16 bf16x8 __attribute__((ext_vector_type(8)));
typedef float f32x4 __attribute__((ext_vector_type(4)));

typedef __attribute__((address_space(1))) void v1_t;
typedef __attribute__((address_space(3))) void v3_t;

// async global->LDS raw copy, 16B/lane; dest = wave-uniform base + lane*16
__device__ __forceinline__ void cp16(void* lds, const void* g) {
  __builtin_amdgcn_global_load_lds((v1_t*)g, (v3_t*)lds, 16, 0, 0);
}

__device__ __forceinline__ f32x4 mfma16(bf16x8 a, bf16x8 b, f32x4 c) {
  return __builtin_amdgcn_mfma_f32_16x16x32_bf16(a, b, c, 0, 0, 0);
}

__device__ __forceinline__ bf16x8 cvt8(float4 a, float4 b) {
  bf16x8 v;
  v[0] = (bf16)a.x; v[1] = (bf16)a.y; v[2] = (bf16)a.z; v[3] = (bf16)a.w;
  v[4] = (bf16)b.x; v[5] = (bf16)b.y; v[6] = (bf16)b.z; v[7] = (bf16)b.w;
  return v;
}

#define SBAR() { __builtin_amdgcn_s_barrier(); __builtin_amdgcn_sched_barrier(0); }
#define WVM4() { asm volatile("s_waitcnt vmcnt(4)" ::: "memory"); }
#define WVM0() { asm volatile("s_waitcnt vmcnt(0)" ::: "memory"); }

// ======== router: logits->softmax->top2->expert lists; fuses x fp32->bf16 conversion ========
__global__ __launch_bounds__(256) void router_kernel(
    const float* __restrict__ x, const float* __restrict__ wr,
    int* __restrict__ counts, int* __restrict__ ids, float* __restrict__ wts,
    bf16* __restrict__ xb)
{
  __shared__ int lcnt[N_EXP];
  __shared__ int gbase[N_EXP];
  __shared__ int s_e0[32], s_l0[32], s_e1[32], s_l1[32];
  __shared__ float s_p0[32], s_p1[32];

  const int tid  = threadIdx.x;
  const int wave = tid >> 6;
  const int lane = tid & 63;
  if (tid < N_EXP) lcnt[tid] = 0;
  __syncthreads();

  for (int it = 0; it < 8; ++it) {
    const int li = it * 4 + wave;
    const int token = blockIdx.x * 32 + li;

    const float4* xrow = (const float4*)(x + (size_t)token * D_MODEL + lane * 16);
    float4 x0 = xrow[0], x1 = xrow[1], x2 = xrow[2], x3 = xrow[3];

    bf16* xd = xb + (size_t)token * D_MODEL + lane * 16;
    *(bf16x8*)xd       = cvt8(x0, x1);
    *(bf16x8*)(xd + 8) = cvt8(x2, x3);

    float logit[N_EXP];
#pragma unroll
    for (int e = 0; e < N_EXP; ++e) {
      const float4* wrow = (const float4*)(wr + e * D_MODEL + lane * 16);
      float4 w0 = wrow[0], w1 = wrow[1], w2 = wrow[2], w3 = wrow[3];
      float s = x0.x*w0.x + x0.y*w0.y + x0.z*w0.z + x0.w*w0.w
              + x1.x*w1.x + x1.y*w1.y + x1.z*w1.z + x1.w*w1.w
              + x2.x*w2.x + x2.y*w2.y + x2.z*w2.z + x2.w*w2.w
              + x3.x*w3.x + x3.y*w3.y + x3.z*w3.z + x3.w*w3.w;
#pragma unroll
      for (int m = 32; m >= 1; m >>= 1) s += __shfl_xor(s, m);
      logit[e] = fminf(fmaxf(s, -1e4f), 1e4f);
    }

    if (lane == 0) {
      float mx = logit[0];
#pragma unroll
      for (int e = 1; e < N_EXP; ++e) mx = fmaxf(mx, logit[e]);
      float ex[N_EXP], sum = 0.f;
#pragma unroll
      for (int e = 0; e < N_EXP; ++e) { ex[e] = expf(logit[e] - mx); sum += ex[e]; }
      float p[N_EXP];
#pragma unroll
      for (int e = 0; e < N_EXP; ++e)
        p[e] = fminf(fmaxf(ex[e] / (sum + 1e-8f), 1e-8f), 1.0f);
      int e0 = 0;
#pragma unroll
      for (int e = 1; e < N_EXP; ++e) if (p[e] > p[e0]) e0 = e;
      int e1 = (e0 == 0) ? 1 : 0;
#pragma unroll
      for (int e = 0; e < N_EXP; ++e) if (e != e0 && p[e] > p[e1]) e1 = e;
      float p0 = p[e0], p1 = p[e1];
      float inv = 1.f / (p0 + p1 + 1e-8f);
      s_e0[li] = e0; s_l0[li] = atomicAdd(&lcnt[e0], 1); s_p0[li] = p0 * inv;
      s_e1[li] = e1; s_l1[li] = atomicAdd(&lcnt[e1], 1); s_p1[li] = p1 * inv;
    }
  }
  __syncthreads();
  if (tid < N_EXP) gbase[tid] = atomicAdd(&counts[tid], lcnt[tid]);
  __syncthreads();
  if (tid < 32) {
    const int token = blockIdx.x * 32 + tid;
    int e0 = s_e0[tid], e1 = s_e1[tid];
    int a = gbase[e0] + s_l0[tid];
    int b = gbase[e1] + s_l1[tid];
    ids[e0 * N_TOK + a] = token; wts[e0 * N_TOK + a] = s_p0[tid];
    ids[e1 * N_TOK + b] = token; wts[e1 * N_TOK + b] = s_p1[tid];
  }
}

__global__ void offsets_kernel(const int* __restrict__ counts, int* __restrict__ offsets) {
  if (threadIdx.x == 0) {
    int r = 0;
#pragma unroll
    for (int e = 0; e < N_EXP; ++e) { offsets[e] = r; r += counts[e]; }
  }
}

// ============ fp32 -> bf16 bulk convert: 32B load / 16B store per thread ============
__global__ __launch_bounds__(256) void cvt_kernel(
    const float* __restrict__ src, bf16* __restrict__ dst, int n8)
{
  int i = blockIdx.x * 256 + threadIdx.x;
  const int stride = gridDim.x * 256;
  for (; i < n8; i += stride) {
    const float4* s = (const float4*)src + 2 * (size_t)i;
    ((bf16x8*)dst)[i] = cvt8(s[0], s[1]);
  }
}

// ====== GEMM1: 256(rows)x256(interleaved gate/up cols) tile, BK=64, 8 waves (2M x 4N),
// double-buffered K-split half-tiles, counted vmcnt(4) (never 0 in steady state),
// raw s_barrier + sched_barrier, LDS XOR swizzle phys = L ^ (((L>>7)&7)<<4),
// SwiGLU fused in epilogue via shfl_xor(1) on interleaved gate/up column pairs.
//
// LDS map (bytes): A[p][kh] at p*32768 + kh*16384 ; B likewise at +65536. Total 128 KiB.
// Stage dest linear (global_load_lds requirement), source pre-inverse-swizzled;
// reads apply the SAME involution to the FULL logical offset (incl. row-parity bit 6).
__global__ __launch_bounds__(512, 2) void gemm1_kernel(
    const bf16* __restrict__ xb, const bf16* __restrict__ wgu,
    const int* __restrict__ counts, const int* __restrict__ offsets,
    const int* __restrict__ ids, bf16* __restrict__ H)
{
  __shared__ char sm[131072];
  const int e = blockIdx.z;
  const int cnt = counts[e];
  const int row0 = blockIdx.y * 256;
  if (row0 >= cnt) return;
  const int c0h = blockIdx.x * 128;          // F-space col tile (128 F cols, x2 interleaved)

  // materialize epilogue-only load NOW so no stray VMEM is outstanding during the
  // counted-vmcnt loop (compiler would otherwise be free to issue it mid-loop)
  const int hbase = offsets[e] + row0;
  asm volatile("" :: "s"(hbase));

  const int tid  = threadIdx.x;
  const int lane = tid & 63;
  const int w    = tid >> 6;                 // wave 0..7
  const int wm   = w >> 2;                   // M half (0..1)
  const int wn   = w & 3;                    // N quarter (0..3)
  const int fr   = lane & 15;
  const int fq   = lane >> 4;

  // ---- stage-source addressing (inverse swizzle) ----
  const int l3   = (lane >> 3) & 7;
  const int cs   = (lane & 7) ^ l3;                        // unswizzled 16B-slot index
  const int rr0  = 2 * (w * 8 + l3) + (cs >> 2);           // tile row (round1: +128)
  const int kofs = (cs & 3) * 8;                           // k-elem offset within 32-elem half

  const int* ide = ids + e * N_TOK;
  const bf16* pa0 = xb + (size_t)ide[min(row0 + rr0,       cnt - 1)] * D_MODEL + kofs;
  const bf16* pa1 = xb + (size_t)ide[min(row0 + rr0 + 128, cnt - 1)] * D_MODEL + kofs;
  const bf16* wge = wgu + (size_t)e * (size_t)D_GU * D_MODEL;
  // B rows interleaved: LDS row r -> weight row c0h + (r>>1) + (r&1)*D_FF
  const int wr0 = c0h + (rr0 >> 1) + (rr0 & 1) * D_FF;
  const bf16* pb0 = wge + (size_t)wr0 * D_MODEL + kofs;
  const bf16* pb1 = pb0 + (size_t)64 * D_MODEL;            // +128 LDS rows = +64 weight rows

  const int stg = w * 1024;                                // + r*8192 within half
  // ---- read-side swizzle: XOR applied to FULL logical offset (bits 4-6) ----
  const int term = ((fr >> 1) & 7) << 4;
  const int rdA = (((wm * 128 + fr) * 64) + fq * 16) ^ term;  // + mf*1024 + kh*16384 + p*32768
  const int rdB = (((wn * 64  + fr) * 64) + fq * 16) ^ term;  // + nf*1024 ... (+65536)

  f32x4 acc[8][4];
#pragma unroll
  for (int i = 0; i < 8; ++i)
#pragma unroll
    for (int j = 0; j < 4; ++j)
#pragma unroll
      for (int k = 0; k < 4; ++k) acc[i][j][k] = 0.f;

  // ---- prologue: stage tile0 (A_k0, B_k0, A_k1, B_k1) into buf 0 ----
  cp16(sm + 0      + stg, pa0);       cp16(sm + 8192           + stg, pa1);
  cp16(sm + 65536  + stg, pb0);       cp16(sm + 65536 + 8192   + stg, pb1);
  cp16(sm + 16384  + stg, pa0 + 32);  cp16(sm + 16384 + 8192   + stg, pa1 + 32);
  cp16(sm + 81920  + stg, pb0 + 32);  cp16(sm + 81920 + 8192   + stg, pb1 + 32);
  WVM4(); SBAR();                     // A_k0,B_k0 landed; A_k1,B_k1 in flight

  const int NT = D_MODEL / 64;        // 16 K-tiles
  for (int kt = 0; kt < NT; ++kt) {
    const int p = kt & 1;
    const char* bufA = sm + p * 32768;
    const char* bufB = sm + 65536 + p * 32768;
    char* nA = sm + (p ^ 1) * 32768;
    char* nB = sm + 65536 + (p ^ 1) * 32768;
    const bool pre = (kt < NT - 1);
    const int ke = (kt + 1) * 64;

    bf16x8 bfr[4], af[4];
    // ---- q0: kh0, m-frags 0-3; stage A_k0(t+1) ----
#pragma unroll
    for (int nf = 0; nf < 4; ++nf) bfr[nf] = *(const bf16x8*)(bufB + nf * 1024 + rdB);
#pragma unroll
    for (int j = 0; j < 4; ++j)    af[j]  = *(const bf16x8*)(bufA + j * 1024 + rdA);
    if (pre) { cp16(nA + stg, pa0 + ke); cp16(nA + 8192 + stg, pa1 + ke); }
    SBAR();
    __builtin_amdgcn_s_setprio(1);
#pragma unroll
    for (int nf = 0; nf < 4; ++nf)
#pragma unroll
      for (int j = 0; j < 4; ++j) acc[j][nf] = mfma16(af[j], bfr[nf], acc[j][nf]);
    __builtin_amdgcn_s_setprio(0);
    SBAR();
    // ---- q1: kh0, m-frags 4-7; stage B_k0(t+1) ----
#pragma unroll
    for (int j = 0; j < 4; ++j) af[j] = *(const bf16x8*)(bufA + (4 + j) * 1024 + rdA);
    if (pre) { cp16(nB + stg, pb0 + ke); cp16(nB + 8192 + stg, pb1 + ke); }
    SBAR();
    __builtin_amdgcn_s_setprio(1);
#pragma unroll
    for (int nf = 0; nf < 4; ++nf)
#pragma unroll
      for (int j = 0; j < 4; ++j) acc[4 + j][nf] = mfma16(af[j], bfr[nf], acc[4 + j][nf]);
    __builtin_amdgcn_s_setprio(0);
    if (pre) { WVM4(); } else { WVM0(); }   // A_k1,B_k1 of THIS tile landed
    SBAR();
    // ---- q2: kh1, m-frags 0-3; stage A_k1(t+1) ----
#pragma unroll
    for (int nf = 0; nf < 4; ++nf) bfr[nf] = *(const bf16x8*)(bufB + 16384 + nf * 1024 + rdB);
#pragma unroll
    for (int j = 0; j < 4; ++j)    af[j]  = *(const bf16x8*)(bufA + 16384 + j * 1024 + rdA);
    if (pre) { cp16(nA + 16384 + stg, pa0 + ke + 32); cp16(nA + 16384 + 8192 + stg, pa1 + ke + 32); }
    SBAR();
    __builtin_amdgcn_s_setprio(1);
#pragma unroll
    for (int nf = 0; nf < 4; ++nf)
#pragma unroll
      for (int j = 0; j < 4; ++j) acc[j][nf] = mfma16(af[j], bfr[nf], acc[j][nf]);
    __builtin_amdgcn_s_setprio(0);
    SBAR();
    // ---- q3: kh1, m-frags 4-7; stage B_k1(t+1) ----
#pragma unroll
    for (int j = 0; j < 4; ++j) af[j] = *(const bf16x8*)(bufA + 16384 + (4 + j) * 1024 + rdA);
    if (pre) { cp16(nB + 16384 + stg, pb0 + ke + 32); cp16(nB + 16384 + 8192 + stg, pb1 + ke + 32); }
    SBAR();
    __builtin_amdgcn_s_setprio(1);
#pragma unroll
    for (int nf = 0; nf < 4; ++nf)
#pragma unroll
      for (int j = 0; j < 4; ++j) acc[4 + j][nf] = mfma16(af[j], bfr[nf], acc[4 + j][nf]);
    __builtin_amdgcn_s_setprio(0);
    if (pre) { WVM4(); SBAR(); }            // A_k0,B_k0 of NEXT tile landed
  }

  // ---- epilogue: SwiGLU across interleaved col pairs (even lane = gate, odd = up) ----
#pragma unroll
  for (int mf = 0; mf < 8; ++mf)
#pragma unroll
    for (int nf = 0; nf < 4; ++nf)
#pragma unroll
      for (int i = 0; i < 4; ++i) {
        float v = acc[mf][nf][i];
        float o = __shfl_xor(v, 1);          // partner column (gate<->up)
        int row = wm * 128 + mf * 16 + fq * 4 + i;
        if (!(fr & 1) && row0 + row < cnt) {
          float h = v * o / (1.f + expf(-o));   // v=gate, o=up
          int f = c0h + wn * 32 + ((nf * 16 + fr) >> 1);
          H[(size_t)(hbase + row) * D_FF + f] = (bf16)h;
        }
      }
}

// ====== GEMM2: H (pitch 2048) @ Wd_b^T -> atomicAdd(w*acc) into fp32 out ======
__global__ __launch_bounds__(256, 2) void gemm2_kernel(
    const bf16* __restrict__ H, const bf16* __restrict__ wdb,
    const int* __restrict__ counts, const int* __restrict__ offsets,
    const int* __restrict__ ids, const float* __restrict__ wts,
    float* __restrict__ out)
{
  const int e = blockIdx.z;
  const int cnt = counts[e];
  const int row0 = blockIdx.y * 128;
  if (row0 >= cnt) return;
  const int c0 = blockIdx.x * 128;
  const int base = offsets[e];

  __shared__ bf16 lA[128 * 32];
  __shared__ bf16 lB[128 * 32];

  const int tid  = threadIdx.x;
  const int lane = tid & 63;
  const int wave = tid >> 6;
  const int l4 = lane >> 2;
  const int kb = (lane & 3) * 8;

  const int ra0 = wave * 16 + l4;
  const int ra1 = (wave + 4) * 16 + l4;
  const int m0 = min(row0 + ra0, cnt - 1);
  const int m1 = min(row0 + ra1, cnt - 1);
  const bf16* srcA0 = H + (size_t)(base + m0) * D_FF + kb;
  const bf16* srcA1 = H + (size_t)(base + m1) * D_FF + kb;
  const bf16* wde = wdb + (size_t)e * D_MODEL * D_FF;
  const bf16* srcB0 = wde + (size_t)(c0 + ra0) * D_FF + kb;
  const bf16* srcB1 = wde + (size_t)(c0 + ra1) * D_FF + kb;

  char* dA0 = (char*)lA + wave * 1024;
  char* dA1 = (char*)lA + (wave + 4) * 1024;
  char* dB0 = (char*)lB + wave * 1024;
  char* dB1 = (char*)lB + (wave + 4) * 1024;

  const int wm = wave >> 1;
  const int wn = wave & 1;
  const int fr = lane & 15;
  const int fq = lane >> 4;
  const bf16* pA = lA + (wm * 64 + fr) * 32 + fq * 8;
  const bf16* pB = lB + (wn * 64 + fr) * 32 + fq * 8;

  f32x4 acc[4][4];
#pragma unroll
  for (int i = 0; i < 4; ++i)
#pragma unroll
    for (int j = 0; j < 4; ++j)
#pragma unroll
      for (int k = 0; k < 4; ++k) acc[i][j][k] = 0.f;

  for (int kt = 0; kt < D_FF / 32; ++kt) {
    cp16(dA0, srcA0); cp16(dA1, srcA1);
    cp16(dB0, srcB0); cp16(dB1, srcB1);
    srcA0 += 32; srcA1 += 32; srcB0 += 32; srcB1 += 32;
    __syncthreads();
    bf16x8 a[4];
#pragma unroll
    for (int fm = 0; fm < 4; ++fm) a[fm] = *(const bf16x8*)(pA + fm * 16 * 32);
#pragma unroll
    for (int fn = 0; fn < 4; ++fn) {
      bf16x8 b = *(const bf16x8*)(pB + fn * 16 * 32);
#pragma unroll
      for (int fm = 0; fm < 4; ++fm) acc[fm][fn] = mfma16(a[fm], b, acc[fm][fn]);
    }
    __syncthreads();
  }

  const int* ide = ids + e * N_TOK;
  const float* wte = wts + e * N_TOK;
#pragma unroll
  for (int fm = 0; fm < 4; ++fm) {
#pragma unroll
    for (int i = 0; i < 4; ++i) {
      int m = wm * 64 + fm * 16 + fq * 4 + i;
      if (row0 + m < cnt) {
        int   tok = ide[row0 + m];
        float wgt = wte[row0 + m];
        float* orow = out + (size_t)tok * D_MODEL;
#pragma unroll
        for (int fn = 0; fn < 4; ++fn) {
          int col = c0 + wn * 64 + fn * 16 + fr;
          atomicAdd(orow + col, wgt * acc[fm][fn][i]);
        }
      }
    }
  }
}

// =========================================================================================
extern "C" void kernel_launch(void* const* d_in, const int* in_sizes, int n_in,
                              void* d_out, int out_size, void* d_ws, size_t ws_size,
                              hipStream_t stream) {
  const float* x   = (const float*)d_in[0];
  const float* wr  = (const float*)d_in[1];
  const float* wgu = (const float*)d_in[2];
  const float* wd  = (const float*)d_in[3];
  float* out = (float*)d_out;

  char* ws = (char*)d_ws;
  int*   counts  = (int*)ws;                             // 32 B
  int*   offsets = (int*)(ws + 64);                      // 32 B
  int*   ids     = (int*)(ws + 4096);                    // 128 KB
  float* wts     = (float*)(ws + 4096 + 131072);         // 128 KB
  bf16*  xb      = (bf16*)(ws + 524288);                 // 8 MB
  bf16*  wgub    = (bf16*)(ws + 524288 + 8388608);       // 64 MB (reused for wdb after gemm1)
  bf16*  wdb     = wgub;                                 // 32 MB alias
  bf16*  H       = (bf16*)(ws + 524288 + 8388608 + 67108864);  // 8192 x 2048 bf16 = 32 MB

  hipMemsetAsync(counts, 0, 64, stream);
  hipMemsetAsync(out, 0, (size_t)N_TOK * D_MODEL * sizeof(float), stream);
  router_kernel<<<N_TOK / 32, 256, 0, stream>>>(x, wr, counts, ids, wts, xb);
  offsets_kernel<<<1, 64, 0, stream>>>(counts, offsets);
  cvt_kernel<<<2048, 256, 0, stream>>>(wgu, wgub, (N_EXP * D_GU * D_MODEL) / 8);
  gemm1_kernel<<<dim3(D_FF / 128, N_TOK / 256, N_EXP), 512, 0, stream>>>(
      xb, wgub, counts, offsets, ids, H);
  cvt_kernel<<<2048, 256, 0, stream>>>(wd, wdb, (N_EXP * D_MODEL * D_FF) / 8);
  gemm2_kernel<<<dim3(D_MODEL / 128, N_TOK / 128, N_EXP), 256, 0, stream>>>(
      H, wdb, counts, offsets, ids, wts, out);
}

// Round 4
// 465.180 us; speedup vs baseline: 1.0936x; 1.0936x over previous
//
#include <hip/hip_runtime.h>
#include <cstdint>

// ---- problem constants (MoEFeedForward: N=4096, D=1024, F=2048, E=8, top-2) ----
#define N_TOK 4096
#define D_MODEL 1024
#define D_FF 2048
#define D_GU 4096          // 2*D_FF: gate_up col space; also GU row pitch
#define N_EXP 8

typedef __bf16 bf16;
typedef __bf16 bf16x8 __attribute__((ext_vector_type(8)));
typedef float f32x4 __attribute__((ext_vector_type(4)));

typedef __attribute__((address_space(1))) void v1_t;
typedef __attribute__((address_space(3))) void v3_t;

// async global->LDS raw copy, 16B/lane; dest = wave-uniform base + lane*16
__device__ __forceinline__ void cp16(void* lds, const void* g) {
  __builtin_amdgcn_global_load_lds((v1_t*)g, (v3_t*)lds, 16, 0, 0);
}

__device__ __forceinline__ f32x4 mfma16(bf16x8 a, bf16x8 b, f32x4 c) {
  return __builtin_amdgcn_mfma_f32_16x16x32_bf16(a, b, c, 0, 0, 0);
}

__device__ __forceinline__ bf16x8 cvt8(float4 a, float4 b) {
  bf16x8 v;
  v[0] = (bf16)a.x; v[1] = (bf16)a.y; v[2] = (bf16)a.z; v[3] = (bf16)a.w;
  v[4] = (bf16)b.x; v[5] = (bf16)b.y; v[6] = (bf16)b.z; v[7] = (bf16)b.w;
  return v;
}

// ======== router + wgu-cvt fused launch ========
// blocks [0,128): routing (32 tokens/block, wave-per-token x 8 iters) + x fp32->bf16.
// blocks [128, grid): grid-stride bulk convert of w_gate_up fp32 -> bf16.
// Both memory-streams run concurrently across CUs; cvt rides under router+HBM.
__global__ __launch_bounds__(256) void router_cvt_kernel(
    const float* __restrict__ x, const float* __restrict__ wr,
    int* __restrict__ counts, int* __restrict__ ids, float* __restrict__ wts,
    bf16* __restrict__ xb, const float* __restrict__ wgu, bf16* __restrict__ wgub)
{
  if (blockIdx.x >= 128) {
    const int n8 = (N_EXP * D_GU * D_MODEL) / 8;
    int i = (blockIdx.x - 128) * 256 + threadIdx.x;
    const int stride = (gridDim.x - 128) * 256;
    for (; i < n8; i += stride) {
      const float4* s = (const float4*)wgu + 2 * (size_t)i;
      ((bf16x8*)wgub)[i] = cvt8(s[0], s[1]);
    }
    return;
  }

  __shared__ int lcnt[N_EXP];
  __shared__ int gbase[N_EXP];
  __shared__ int s_e0[32], s_l0[32], s_e1[32], s_l1[32];
  __shared__ float s_p0[32], s_p1[32];

  const int tid  = threadIdx.x;
  const int wave = tid >> 6;
  const int lane = tid & 63;
  if (tid < N_EXP) lcnt[tid] = 0;
  __syncthreads();

  for (int it = 0; it < 8; ++it) {
    const int li = it * 4 + wave;                 // local token 0..31
    const int token = blockIdx.x * 32 + li;

    const float4* xrow = (const float4*)(x + (size_t)token * D_MODEL + lane * 16);
    float4 x0 = xrow[0], x1 = xrow[1], x2 = xrow[2], x3 = xrow[3];

    bf16* xd = xb + (size_t)token * D_MODEL + lane * 16;
    *(bf16x8*)xd       = cvt8(x0, x1);
    *(bf16x8*)(xd + 8) = cvt8(x2, x3);

    float logit[N_EXP];
#pragma unroll
    for (int e = 0; e < N_EXP; ++e) {
      const float4* wrow = (const float4*)(wr + e * D_MODEL + lane * 16);
      float4 w0 = wrow[0], w1 = wrow[1], w2 = wrow[2], w3 = wrow[3];
      float s = x0.x*w0.x + x0.y*w0.y + x0.z*w0.z + x0.w*w0.w
              + x1.x*w1.x + x1.y*w1.y + x1.z*w1.z + x1.w*w1.w
              + x2.x*w2.x + x2.y*w2.y + x2.z*w2.z + x2.w*w2.w
              + x3.x*w3.x + x3.y*w3.y + x3.z*w3.z + x3.w*w3.w;
#pragma unroll
      for (int m = 32; m >= 1; m >>= 1) s += __shfl_xor(s, m);
      logit[e] = fminf(fmaxf(s, -1e4f), 1e4f);    // reference CLAMP
    }

    if (lane == 0) {
      float mx = logit[0];
#pragma unroll
      for (int e = 1; e < N_EXP; ++e) mx = fmaxf(mx, logit[e]);
      float ex[N_EXP], sum = 0.f;
#pragma unroll
      for (int e = 0; e < N_EXP; ++e) { ex[e] = expf(logit[e] - mx); sum += ex[e]; }
      float p[N_EXP];
#pragma unroll
      for (int e = 0; e < N_EXP; ++e)
        p[e] = fminf(fmaxf(ex[e] / (sum + 1e-8f), 1e-8f), 1.0f);
      int e0 = 0;
#pragma unroll
      for (int e = 1; e < N_EXP; ++e) if (p[e] > p[e0]) e0 = e;
      int e1 = (e0 == 0) ? 1 : 0;
#pragma unroll
      for (int e = 0; e < N_EXP; ++e) if (e != e0 && p[e] > p[e1]) e1 = e;
      float p0 = p[e0], p1 = p[e1];
      float inv = 1.f / (p0 + p1 + 1e-8f);
      s_e0[li] = e0; s_l0[li] = atomicAdd(&lcnt[e0], 1); s_p0[li] = p0 * inv;
      s_e1[li] = e1; s_l1[li] = atomicAdd(&lcnt[e1], 1); s_p1[li] = p1 * inv;
    }
  }
  __syncthreads();
  if (tid < N_EXP) gbase[tid] = atomicAdd(&counts[tid], lcnt[tid]);
  __syncthreads();
  if (tid < 32) {
    const int token = blockIdx.x * 32 + tid;
    int e0 = s_e0[tid], e1 = s_e1[tid];
    int a = gbase[e0] + s_l0[tid];
    int b = gbase[e1] + s_l1[tid];
    ids[e0 * N_TOK + a] = token; wts[e0 * N_TOK + a] = s_p0[tid];
    ids[e1 * N_TOK + b] = token; wts[e1 * N_TOK + b] = s_p1[tid];
  }
}

__global__ void offsets_kernel(const int* __restrict__ counts, int* __restrict__ offsets) {
  if (threadIdx.x == 0) {
    int r = 0;
#pragma unroll
    for (int e = 0; e < N_EXP; ++e) { offsets[e] = r; r += counts[e]; }
  }
}

// ====== GEMM1a: gathered xb @ Wgu_b^T -> GU bf16 (compacted rows, pitch 4096) ======
// m97 pattern: 128x128 tile, BK=32, 64-AGPR accumulator. launch_bounds(256,4):
// forces allocator to the 128-total-reg boundary -> 4 blocks/CU (m69 cliff).
__global__ __launch_bounds__(256, 4) void gemm1a_kernel(
    const bf16* __restrict__ xb, const bf16* __restrict__ wgu,
    const int* __restrict__ counts, const int* __restrict__ offsets,
    const int* __restrict__ ids, bf16* __restrict__ GU)
{
  const int e = blockIdx.z;
  const int cnt = counts[e];
  const int row0 = blockIdx.y * 128;
  if (row0 >= cnt) return;
  const int c0 = blockIdx.x * 128;              // gate_up col tile in [0, 4096)

  __shared__ bf16 lA[128 * 32];
  __shared__ bf16 lB[128 * 32];

  const int tid  = threadIdx.x;
  const int lane = tid & 63;
  const int wave = tid >> 6;
  const int l4 = lane >> 2;
  const int kb = (lane & 3) * 8;

  const int ra0 = wave * 16 + l4;
  const int ra1 = (wave + 4) * 16 + l4;

  const int* ide = ids + e * N_TOK;
  const int m0 = min(row0 + ra0, cnt - 1);
  const int m1 = min(row0 + ra1, cnt - 1);
  const bf16* srcA0 = xb + (size_t)ide[m0] * D_MODEL + kb;
  const bf16* srcA1 = xb + (size_t)ide[m1] * D_MODEL + kb;
  const bf16* wge = wgu + (size_t)e * D_GU * D_MODEL;
  const bf16* srcB0 = wge + (size_t)(c0 + ra0) * D_MODEL + kb;
  const bf16* srcB1 = wge + (size_t)(c0 + ra1) * D_MODEL + kb;

  char* dA0 = (char*)lA + wave * 1024;
  char* dA1 = (char*)lA + (wave + 4) * 1024;
  char* dB0 = (char*)lB + wave * 1024;
  char* dB1 = (char*)lB + (wave + 4) * 1024;

  const int wm = wave >> 1;
  const int wn = wave & 1;
  const int fr = lane & 15;
  const int fq = lane >> 4;
  const bf16* pA = lA + (wm * 64 + fr) * 32 + fq * 8;
  const bf16* pB = lB + (wn * 64 + fr) * 32 + fq * 8;

  f32x4 acc[4][4];
#pragma unroll
  for (int i = 0; i < 4; ++i)
#pragma unroll
    for (int j = 0; j < 4; ++j)
#pragma unroll
      for (int k = 0; k < 4; ++k) acc[i][j][k] = 0.f;

  for (int kt = 0; kt < D_MODEL / 32; ++kt) {
    cp16(dA0, srcA0); cp16(dA1, srcA1);
    cp16(dB0, srcB0); cp16(dB1, srcB1);
    srcA0 += 32; srcA1 += 32; srcB0 += 32; srcB1 += 32;
    __syncthreads();
    bf16x8 a[4];
#pragma unroll
    for (int fm = 0; fm < 4; ++fm) a[fm] = *(const bf16x8*)(pA + fm * 16 * 32);
#pragma unroll
    for (int fn = 0; fn < 4; ++fn) {
      bf16x8 b = *(const bf16x8*)(pB + fn * 16 * 32);
#pragma unroll
      for (int fm = 0; fm < 4; ++fm) acc[fm][fn] = mfma16(a[fm], b, acc[fm][fn]);
    }
    __syncthreads();
  }

  const int hbase = offsets[e] + row0;
#pragma unroll
  for (int fm = 0; fm < 4; ++fm) {
#pragma unroll
    for (int fn = 0; fn < 4; ++fn) {
#pragma unroll
      for (int i = 0; i < 4; ++i) {
        int m = wm * 64 + fm * 16 + fq * 4 + i;   // C/D: row = quad*4+reg
        if (row0 + m < cnt) {
          int col = c0 + wn * 64 + fn * 16 + fr;  // C/D: col = lane&15
          GU[(size_t)(hbase + m) * D_GU + col] = (bf16)acc[fm][fn][i];
        }
      }
    }
  }
}

// ====== SwiGLU in-place + wd-cvt fused launch ======
// blocks [0,8192): GU[r][j] (gate half) <- silu(GU[r][2048+j]) * GU[r][j]
// blocks [8192, grid): grid-stride bulk convert of w_down fp32 -> bf16.
__global__ __launch_bounds__(256) void swiglu_cvt_kernel(
    bf16* __restrict__ GU, const float* __restrict__ wd, bf16* __restrict__ wdb)
{
  if (blockIdx.x >= 8192) {
    const int n8 = (N_EXP * D_MODEL * D_FF) / 8;
    int i = (blockIdx.x - 8192) * 256 + threadIdx.x;
    const int stride = (gridDim.x - 8192) * 256;
    for (; i < n8; i += stride) {
      const float4* s = (const float4*)wd + 2 * (size_t)i;
      ((bf16x8*)wdb)[i] = cvt8(s[0], s[1]);
    }
    return;
  }
  // 8192 rows x 2048 cols, 8 cols/thread (all compacted rows valid: sum(counts)=8192)
  const int idx = blockIdx.x * 256 + threadIdx.x;
  const int row = idx >> 8;                 // 256 groups of 8 per row
  const int col = (idx & 255) * 8;
  bf16* g = GU + (size_t)row * D_GU + col;
  bf16x8 g8 = *(const bf16x8*)g;
  bf16x8 u8 = *(const bf16x8*)(g + D_FF);
  bf16x8 h;
#pragma unroll
  for (int j = 0; j < 8; ++j) {
    float u = (float)u8[j];
    float gg = (float)g8[j];
    h[j] = (bf16)(gg * u / (1.f + expf(-u)));
  }
  *(bf16x8*)g = h;
}

// ====== GEMM2: H(=GU gate half, pitch 4096) @ Wd_b^T -> atomicAdd(w*acc) into fp32 out ======
__global__ __launch_bounds__(256, 4) void gemm2_kernel(
    const bf16* __restrict__ GU, const bf16* __restrict__ wdb,
    const int* __restrict__ counts, const int* __restrict__ offsets,
    const int* __restrict__ ids, const float* __restrict__ wts,
    float* __restrict__ out)
{
  const int e = blockIdx.z;
  const int cnt = counts[e];
  const int row0 = blockIdx.y * 128;
  if (row0 >= cnt) return;
  const int c0 = blockIdx.x * 128;              // output col tile in [0, 1024)
  const int base = offsets[e];

  __shared__ bf16 lA[128 * 32];
  __shared__ bf16 lB[128 * 32];

  const int tid  = threadIdx.x;
  const int lane = tid & 63;
  const int wave = tid >> 6;
  const int l4 = lane >> 2;
  const int kb = (lane & 3) * 8;

  const int ra0 = wave * 16 + l4;
  const int ra1 = (wave + 4) * 16 + l4;
  const int m0 = min(row0 + ra0, cnt - 1);
  const int m1 = min(row0 + ra1, cnt - 1);
  const bf16* srcA0 = GU + (size_t)(base + m0) * D_GU + kb;   // pitch 4096, K in [0,2048)
  const bf16* srcA1 = GU + (size_t)(base + m1) * D_GU + kb;
  const bf16* wde = wdb + (size_t)e * D_MODEL * D_FF;
  const bf16* srcB0 = wde + (size_t)(c0 + ra0) * D_FF + kb;
  const bf16* srcB1 = wde + (size_t)(c0 + ra1) * D_FF + kb;

  char* dA0 = (char*)lA + wave * 1024;
  char* dA1 = (char*)lA + (wave + 4) * 1024;
  char* dB0 = (char*)lB + wave * 1024;
  char* dB1 = (char*)lB + (wave + 4) * 1024;

  const int wm = wave >> 1;
  const int wn = wave & 1;
  const int fr = lane & 15;
  const int fq = lane >> 4;
  const bf16* pA = lA + (wm * 64 + fr) * 32 + fq * 8;
  const bf16* pB = lB + (wn * 64 + fr) * 32 + fq * 8;

  f32x4 acc[4][4];
#pragma unroll
  for (int i = 0; i < 4; ++i)
#pragma unroll
    for (int j = 0; j < 4; ++j)
#pragma unroll
      for (int k = 0; k < 4; ++k) acc[i][j][k] = 0.f;

  for (int kt = 0; kt < D_FF / 32; ++kt) {
    cp16(dA0, srcA0); cp16(dA1, srcA1);
    cp16(dB0, srcB0); cp16(dB1, srcB1);
    srcA0 += 32; srcA1 += 32; srcB0 += 32; srcB1 += 32;
    __syncthreads();
    bf16x8 a[4];
#pragma unroll
    for (int fm = 0; fm < 4; ++fm) a[fm] = *(const bf16x8*)(pA + fm * 16 * 32);
#pragma unroll
    for (int fn = 0; fn < 4; ++fn) {
      bf16x8 b = *(const bf16x8*)(pB + fn * 16 * 32);
#pragma unroll
      for (int fm = 0; fm < 4; ++fm) acc[fm][fn] = mfma16(a[fm], b, acc[fm][fn]);
    }
    __syncthreads();
  }

  const int* ide = ids + e * N_TOK;
  const float* wte = wts + e * N_TOK;
#pragma unroll
  for (int fm = 0; fm < 4; ++fm) {
#pragma unroll
    for (int i = 0; i < 4; ++i) {
      int m = wm * 64 + fm * 16 + fq * 4 + i;
      if (row0 + m < cnt) {
        int   tok = ide[row0 + m];
        float w   = wte[row0 + m];
        float* orow = out + (size_t)tok * D_MODEL;
#pragma unroll
        for (int fn = 0; fn < 4; ++fn) {
          int col = c0 + wn * 64 + fn * 16 + fr;
          atomicAdd(orow + col, w * acc[fm][fn][i]);
        }
      }
    }
  }
}

// =========================================================================================
extern "C" void kernel_launch(void* const* d_in, const int* in_sizes, int n_in,
                              void* d_out, int out_size, void* d_ws, size_t ws_size,
                              hipStream_t stream) {
  const float* x   = (const float*)d_in[0];
  const float* wr  = (const float*)d_in[1];
  const float* wgu = (const float*)d_in[2];
  const float* wd  = (const float*)d_in[3];
  float* out = (float*)d_out;

  char* ws = (char*)d_ws;
  // workspace layout — ~136.5 MB total
  int*   counts  = (int*)ws;                             // 32 B
  int*   offsets = (int*)(ws + 64);                      // 32 B
  int*   ids     = (int*)(ws + 4096);                    // 128 KB
  float* wts     = (float*)(ws + 4096 + 131072);         // 128 KB
  bf16*  xb      = (bf16*)(ws + 524288);                 // 8 MB
  bf16*  wgub    = (bf16*)(ws + 524288 + 8388608);       // 64 MB (reused for wdb after gemm1a)
  bf16*  wdb     = wgub;                                 // 32 MB alias (wgub dead post-gemm1a)
  bf16*  GU      = (bf16*)(ws + 524288 + 8388608 + 67108864);  // 8192 x 4096 bf16 = 64 MB

  hipMemsetAsync(counts, 0, 64, stream);
  hipMemsetAsync(out, 0, (size_t)N_TOK * D_MODEL * sizeof(float), stream);
  // router (128 blocks) + wgu-cvt (1920 blocks) in one launch
  router_cvt_kernel<<<2048, 256, 0, stream>>>(x, wr, counts, ids, wts, xb, wgu, wgub);
  offsets_kernel<<<1, 64, 0, stream>>>(counts, offsets);
  gemm1a_kernel<<<dim3(D_GU / 128, N_TOK / 128, N_EXP), 256, 0, stream>>>(
      xb, wgub, counts, offsets, ids, GU);
  // swiglu (8192 blocks) + wd-cvt (2048 blocks) in one launch
  swiglu_cvt_kernel<<<10240, 256, 0, stream>>>(GU, wd, wdb);
  gemm2_kernel<<<dim3(D_MODEL / 128, N_TOK / 128, N_EXP), 256, 0, stream>>>(
      GU, wdb, counts, offsets, ids, wts, out);
}

// Round 6
// 450.327 us; speedup vs baseline: 1.1297x; 1.0330x over previous
//
#include <hip/hip_runtime.h>
#include <cstdint>

// ---- problem constants (MoEFeedForward: N=4096, D=1024, F=2048, E=8, top-2) ----
#define N_TOK 4096
#define D_MODEL 1024
#define D_FF 2048
#define D_GU 4096          // 2*D_FF: gate_up col space; also GU row pitch
#define N_EXP 8

typedef __bf16 bf16;
typedef __bf16 bf16x8 __attribute__((ext_vector_type(8)));
typedef float f32x4 __attribute__((ext_vector_type(4)));

typedef __attribute__((address_space(1))) void v1_t;
typedef __attribute__((address_space(3))) void v3_t;

// async global->LDS raw copy, 16B/lane; dest = wave-uniform base + lane*16
__device__ __forceinline__ void cp16(void* lds, const void* g) {
  __builtin_amdgcn_global_load_lds((v1_t*)g, (v3_t*)lds, 16, 0, 0);
}

__device__ __forceinline__ f32x4 mfma16(bf16x8 a, bf16x8 b, f32x4 c) {
  return __builtin_amdgcn_mfma_f32_16x16x32_bf16(a, b, c, 0, 0, 0);
}

__device__ __forceinline__ bf16x8 cvt8(float4 a, float4 b) {
  bf16x8 v;
  v[0] = (bf16)a.x; v[1] = (bf16)a.y; v[2] = (bf16)a.z; v[3] = (bf16)a.w;
  v[4] = (bf16)b.x; v[5] = (bf16)b.y; v[6] = (bf16)b.z; v[7] = (bf16)b.w;
  return v;
}

// ======== router + wgu-cvt fused launch ========
__global__ __launch_bounds__(256) void router_cvt_kernel(
    const float* __restrict__ x, const float* __restrict__ wr,
    int* __restrict__ counts, int* __restrict__ ids, float* __restrict__ wts,
    bf16* __restrict__ xb, const float* __restrict__ wgu, bf16* __restrict__ wgub)
{
  if (blockIdx.x >= 128) {
    const int n8 = (N_EXP * D_GU * D_MODEL) / 8;
    int i = (blockIdx.x - 128) * 256 + threadIdx.x;
    const int stride = (gridDim.x - 128) * 256;
    for (; i < n8; i += stride) {
      const float4* s = (const float4*)wgu + 2 * (size_t)i;
      ((bf16x8*)wgub)[i] = cvt8(s[0], s[1]);
    }
    return;
  }

  __shared__ int lcnt[N_EXP];
  __shared__ int gbase[N_EXP];
  __shared__ int s_e0[32], s_l0[32], s_e1[32], s_l1[32];
  __shared__ float s_p0[32], s_p1[32];

  const int tid  = threadIdx.x;
  const int wave = tid >> 6;
  const int lane = tid & 63;
  if (tid < N_EXP) lcnt[tid] = 0;
  __syncthreads();

  for (int it = 0; it < 8; ++it) {
    const int li = it * 4 + wave;                 // local token 0..31
    const int token = blockIdx.x * 32 + li;

    const float4* xrow = (const float4*)(x + (size_t)token * D_MODEL + lane * 16);
    float4 x0 = xrow[0], x1 = xrow[1], x2 = xrow[2], x3 = xrow[3];

    bf16* xd = xb + (size_t)token * D_MODEL + lane * 16;
    *(bf16x8*)xd       = cvt8(x0, x1);
    *(bf16x8*)(xd + 8) = cvt8(x2, x3);

    float logit[N_EXP];
#pragma unroll
    for (int e = 0; e < N_EXP; ++e) {
      const float4* wrow = (const float4*)(wr + e * D_MODEL + lane * 16);
      float4 w0 = wrow[0], w1 = wrow[1], w2 = wrow[2], w3 = wrow[3];
      float s = x0.x*w0.x + x0.y*w0.y + x0.z*w0.z + x0.w*w0.w
              + x1.x*w1.x + x1.y*w1.y + x1.z*w1.z + x1.w*w1.w
              + x2.x*w2.x + x2.y*w2.y + x2.z*w2.z + x2.w*w2.w
              + x3.x*w3.x + x3.y*w3.y + x3.z*w3.z + x3.w*w3.w;
#pragma unroll
      for (int m = 32; m >= 1; m >>= 1) s += __shfl_xor(s, m);
      logit[e] = fminf(fmaxf(s, -1e4f), 1e4f);    // reference CLAMP
    }

    if (lane == 0) {
      float mx = logit[0];
#pragma unroll
      for (int e = 1; e < N_EXP; ++e) mx = fmaxf(mx, logit[e]);
      float ex[N_EXP], sum = 0.f;
#pragma unroll
      for (int e = 0; e < N_EXP; ++e) { ex[e] = expf(logit[e] - mx); sum += ex[e]; }
      float p[N_EXP];
#pragma unroll
      for (int e = 0; e < N_EXP; ++e)
        p[e] = fminf(fmaxf(ex[e] / (sum + 1e-8f), 1e-8f), 1.0f);
      int e0 = 0;
#pragma unroll
      for (int e = 1; e < N_EXP; ++e) if (p[e] > p[e0]) e0 = e;
      int e1 = (e0 == 0) ? 1 : 0;
#pragma unroll
      for (int e = 0; e < N_EXP; ++e) if (e != e0 && p[e] > p[e1]) e1 = e;
      float p0 = p[e0], p1 = p[e1];
      float inv = 1.f / (p0 + p1 + 1e-8f);
      s_e0[li] = e0; s_l0[li] = atomicAdd(&lcnt[e0], 1); s_p0[li] = p0 * inv;
      s_e1[li] = e1; s_l1[li] = atomicAdd(&lcnt[e1], 1); s_p1[li] = p1 * inv;
    }
  }
  __syncthreads();
  if (tid < N_EXP) gbase[tid] = atomicAdd(&counts[tid], lcnt[tid]);
  __syncthreads();
  if (tid < 32) {
    const int token = blockIdx.x * 32 + tid;
    int e0 = s_e0[tid], e1 = s_e1[tid];
    int a = gbase[e0] + s_l0[tid];
    int b = gbase[e1] + s_l1[tid];
    ids[e0 * N_TOK + a] = token; wts[e0 * N_TOK + a] = s_p0[tid];
    ids[e1 * N_TOK + b] = token; wts[e1 * N_TOK + b] = s_p1[tid];
  }
}

__global__ void offsets_kernel(const int* __restrict__ counts, int* __restrict__ offsets) {
  if (threadIdx.x == 0) {
    int r = 0;
#pragma unroll
    for (int e = 0; e < N_EXP; ++e) { offsets[e] = r; r += counts[e]; }
  }
}

// ====== GEMM1a: gathered xb @ Wgu_b^T -> GU bf16 (compacted rows, pitch 4096) ======
// 128x128 tile, BK=64 (16 K-steps: half the barrier count of BK=32), LDS 32 KB.
// Bank-conflict-free via XOR involution phys_slot = log_slot ^ (row&7) on 128B rows:
// global SOURCE k-slot pre-inverse-swizzled ((l&7)^(l>>3)), reads swizzled with
// ko = (kk*64 + fq*16) ^ ((fr&7)<<4). Both sides verified as the same involution;
// XOR confined to bits 4-6 of the sub-row offset (no carry escape; ko < 128).
__global__ __launch_bounds__(256, 2) void gemm1a_kernel(
    const bf16* __restrict__ xb, const bf16* __restrict__ wgu,
    const int* __restrict__ counts, const int* __restrict__ offsets,
    const int* __restrict__ ids, bf16* __restrict__ GU)
{
  const int e = blockIdx.z;
  const int cnt = counts[e];
  const int row0 = blockIdx.y * 128;
  if (row0 >= cnt) return;
  const int c0 = blockIdx.x * 128;              // gate_up col tile in [0, 4096)

  __shared__ bf16 lA[128 * 64];
  __shared__ bf16 lB[128 * 64];

  const int tid  = threadIdx.x;
  const int lane = tid & 63;
  const int w    = tid >> 6;                        // wave 0..3
  const int l8   = lane >> 3;                       // row-within-pass 0..7
  const int ssrc = ((lane & 7) ^ l8) * 8;           // inverse-swizzled k-elem offset

  const int* ide = ids + e * N_TOK;
  const bf16* wge = wgu + (size_t)e * D_GU * D_MODEL;
  const bf16* srcA[4];
  const bf16* srcB[4];
#pragma unroll
  for (int p = 0; p < 4; ++p) {
    const int r = w * 32 + p * 8 + l8;              // LDS tile row 0..127
    srcA[p] = xb  + (size_t)ide[min(row0 + r, cnt - 1)] * D_MODEL + ssrc;
    srcB[p] = wge + (size_t)(c0 + r) * D_MODEL + ssrc;
  }
  char* const dA = (char*)lA + w * 4096;            // + p*1024; dest = base + lane*16
  char* const dB = (char*)lB + w * 4096;

  const int wm = w >> 1;
  const int wn = w & 1;
  const int fr = lane & 15;
  const int fq = lane >> 4;
  const char* pAr = (const char*)lA + (wm * 64 + fr) * 128;   // + fm*2048 + ko
  const char* pBr = (const char*)lB + (wn * 64 + fr) * 128;   // + fn*2048 + ko
  const int ko0 = (fq << 4) ^ ((fr & 7) << 4);                // kk=0 swizzled k-offset
  const int ko1 = (64 + (fq << 4)) ^ ((fr & 7) << 4);         // kk=1

  f32x4 acc[4][4];
#pragma unroll
  for (int i = 0; i < 4; ++i)
#pragma unroll
    for (int j = 0; j < 4; ++j)
#pragma unroll
      for (int k = 0; k < 4; ++k) acc[i][j][k] = 0.f;

  for (int kt = 0; kt < D_MODEL / 64; ++kt) {
#pragma unroll
    for (int p = 0; p < 4; ++p) cp16(dA + p * 1024, srcA[p]);
#pragma unroll
    for (int p = 0; p < 4; ++p) cp16(dB + p * 1024, srcB[p]);
#pragma unroll
    for (int p = 0; p < 4; ++p) { srcA[p] += 64; srcB[p] += 64; }
    __syncthreads();
    {
      bf16x8 a[4];
#pragma unroll
      for (int fm = 0; fm < 4; ++fm) a[fm] = *(const bf16x8*)(pAr + fm * 2048 + ko0);
#pragma unroll
      for (int fn = 0; fn < 4; ++fn) {
        bf16x8 b = *(const bf16x8*)(pBr + fn * 2048 + ko0);
#pragma unroll
        for (int fm = 0; fm < 4; ++fm) acc[fm][fn] = mfma16(a[fm], b, acc[fm][fn]);
      }
#pragma unroll
      for (int fm = 0; fm < 4; ++fm) a[fm] = *(const bf16x8*)(pAr + fm * 2048 + ko1);
#pragma unroll
      for (int fn = 0; fn < 4; ++fn) {
        bf16x8 b = *(const bf16x8*)(pBr + fn * 2048 + ko1);
#pragma unroll
        for (int fm = 0; fm < 4; ++fm) acc[fm][fn] = mfma16(a[fm], b, acc[fm][fn]);
      }
    }
    __syncthreads();
  }

  const int hbase = offsets[e] + row0;
#pragma unroll
  for (int fm = 0; fm < 4; ++fm) {
#pragma unroll
    for (int fn = 0; fn < 4; ++fn) {
#pragma unroll
      for (int i = 0; i < 4; ++i) {
        int m = wm * 64 + fm * 16 + fq * 4 + i;   // C/D: row = quad*4+reg
        if (row0 + m < cnt) {
          int col = c0 + wn * 64 + fn * 16 + fr;  // C/D: col = lane&15
          GU[(size_t)(hbase + m) * D_GU + col] = (bf16)acc[fm][fn][i];
        }
      }
    }
  }
}

// ====== SwiGLU in-place + wd-cvt fused launch ======
__global__ __launch_bounds__(256) void swiglu_cvt_kernel(
    bf16* __restrict__ GU, const float* __restrict__ wd, bf16* __restrict__ wdb)
{
  if (blockIdx.x >= 8192) {
    const int n8 = (N_EXP * D_MODEL * D_FF) / 8;
    int i = (blockIdx.x - 8192) * 256 + threadIdx.x;
    const int stride = (gridDim.x - 8192) * 256;
    for (; i < n8; i += stride) {
      const float4* s = (const float4*)wd + 2 * (size_t)i;
      ((bf16x8*)wdb)[i] = cvt8(s[0], s[1]);
    }
    return;
  }
  const int idx = blockIdx.x * 256 + threadIdx.x;
  const int row = idx >> 8;
  const int col = (idx & 255) * 8;
  bf16* g = GU + (size_t)row * D_GU + col;
  bf16x8 g8 = *(const bf16x8*)g;
  bf16x8 u8 = *(const bf16x8*)(g + D_FF);
  bf16x8 h;
#pragma unroll
  for (int j = 0; j < 8; ++j) {
    float u = (float)u8[j];
    float gg = (float)g8[j];
    h[j] = (bf16)(gg * u / (1.f + expf(-u)));
  }
  *(bf16x8*)g = h;
}

// ====== GEMM2: H(=GU gate half, pitch 4096) @ Wd_b^T, split-K x2 ->
//        atomicAdd(w*partial) into fp32 out. BK=64, same swizzled LDS as gemm1a. ======
__global__ __launch_bounds__(256, 2) void gemm2_kernel(
    const bf16* __restrict__ GU, const bf16* __restrict__ wdb,
    const int* __restrict__ counts, const int* __restrict__ offsets,
    const int* __restrict__ ids, const float* __restrict__ wts,
    float* __restrict__ out)
{
  const int e = blockIdx.z;
  const int cnt = counts[e];
  const int row0 = blockIdx.y * 128;
  if (row0 >= cnt) return;
  const int c0 = (blockIdx.x & 7) * 128;        // output col tile in [0, 1024)
  const int kh = blockIdx.x >> 3;               // K half: [kh*1024, kh*1024+1024)
  const int base = offsets[e];

  __shared__ bf16 lA[128 * 64];
  __shared__ bf16 lB[128 * 64];

  const int tid  = threadIdx.x;
  const int lane = tid & 63;
  const int w    = tid >> 6;
  const int l8   = lane >> 3;
  const int ssrc = ((lane & 7) ^ l8) * 8;

  const bf16* wde = wdb + (size_t)e * D_MODEL * D_FF;
  const bf16* srcA[4];
  const bf16* srcB[4];
#pragma unroll
  for (int p = 0; p < 4; ++p) {
    const int r = w * 32 + p * 8 + l8;
    srcA[p] = GU  + (size_t)(base + min(row0 + r, cnt - 1)) * D_GU + kh * 1024 + ssrc;
    srcB[p] = wde + (size_t)(c0 + r) * D_FF + kh * 1024 + ssrc;
  }
  char* const dA = (char*)lA + w * 4096;
  char* const dB = (char*)lB + w * 4096;

  const int wm = w >> 1;
  const int wn = w & 1;
  const int fr = lane & 15;
  const int fq = lane >> 4;
  const char* pAr = (const char*)lA + (wm * 64 + fr) * 128;
  const char* pBr = (const char*)lB + (wn * 64 + fr) * 128;
  const int ko0 = (fq << 4) ^ ((fr & 7) << 4);
  const int ko1 = (64 + (fq << 4)) ^ ((fr & 7) << 4);

  f32x4 acc[4][4];
#pragma unroll
  for (int i = 0; i < 4; ++i)
#pragma unroll
    for (int j = 0; j < 4; ++j)
#pragma unroll
      for (int k = 0; k < 4; ++k) acc[i][j][k] = 0.f;

  for (int kt = 0; kt < 1024 / 64; ++kt) {      // 16 steps per K-half
#pragma unroll
    for (int p = 0; p < 4; ++p) cp16(dA + p * 1024, srcA[p]);
#pragma unroll
    for (int p = 0; p < 4; ++p) cp16(dB + p * 1024, srcB[p]);
#pragma unroll
    for (int p = 0; p < 4; ++p) { srcA[p] += 64; srcB[p] += 64; }
    __syncthreads();
    {
      bf16x8 a[4];
#pragma unroll
      for (int fm = 0; fm < 4; ++fm) a[fm] = *(const bf16x8*)(pAr + fm * 2048 + ko0);
#pragma unroll
      for (int fn = 0; fn < 4; ++fn) {
        bf16x8 b = *(const bf16x8*)(pBr + fn * 2048 + ko0);
#pragma unroll
        for (int fm = 0; fm < 4; ++fm) acc[fm][fn] = mfma16(a[fm], b, acc[fm][fn]);
      }
#pragma unroll
      for (int fm = 0; fm < 4; ++fm) a[fm] = *(const bf16x8*)(pAr + fm * 2048 + ko1);
#pragma unroll
      for (int fn = 0; fn < 4; ++fn) {
        bf16x8 b = *(const bf16x8*)(pBr + fn * 2048 + ko1);
#pragma unroll
        for (int fm = 0; fm < 4; ++fm) acc[fm][fn] = mfma16(a[fm], b, acc[fm][fn]);
      }
    }
    __syncthreads();
  }

  const int* ide = ids + e * N_TOK;
  const float* wte = wts + e * N_TOK;
#pragma unroll
  for (int fm = 0; fm < 4; ++fm) {
#pragma unroll
    for (int i = 0; i < 4; ++i) {
      int m = wm * 64 + fm * 16 + fq * 4 + i;
      if (row0 + m < cnt) {
        int   tok = ide[row0 + m];
        float wgt = wte[row0 + m];
        float* orow = out + (size_t)tok * D_MODEL;
#pragma unroll
        for (int fn = 0; fn < 4; ++fn) {
          int col = c0 + wn * 64 + fn * 16 + fr;
          atomicAdd(orow + col, wgt * acc[fm][fn][i]);
        }
      }
    }
  }
}

// =========================================================================================
extern "C" void kernel_launch(void* const* d_in, const int* in_sizes, int n_in,
                              void* d_out, int out_size, void* d_ws, size_t ws_size,
                              hipStream_t stream) {
  const float* x   = (const float*)d_in[0];
  const float* wr  = (const float*)d_in[1];
  const float* wgu = (const float*)d_in[2];
  const float* wd  = (const float*)d_in[3];
  float* out = (float*)d_out;

  char* ws = (char*)d_ws;
  int*   counts  = (int*)ws;                             // 32 B
  int*   offsets = (int*)(ws + 64);                      // 32 B
  int*   ids     = (int*)(ws + 4096);                    // 128 KB
  float* wts     = (float*)(ws + 4096 + 131072);         // 128 KB
  bf16*  xb      = (bf16*)(ws + 524288);                 // 8 MB
  bf16*  wgub    = (bf16*)(ws + 524288 + 8388608);       // 64 MB (reused for wdb after gemm1a)
  bf16*  wdb     = wgub;                                 // 32 MB alias (wgub dead post-gemm1a)
  bf16*  GU      = (bf16*)(ws + 524288 + 8388608 + 67108864);  // 8192 x 4096 bf16 = 64 MB

  hipMemsetAsync(counts, 0, 64, stream);
  hipMemsetAsync(out, 0, (size_t)N_TOK * D_MODEL * sizeof(float), stream);
  router_cvt_kernel<<<2048, 256, 0, stream>>>(x, wr, counts, ids, wts, xb, wgu, wgub);
  offsets_kernel<<<1, 64, 0, stream>>>(counts, offsets);
  gemm1a_kernel<<<dim3(D_GU / 128, N_TOK / 128, N_EXP), 256, 0, stream>>>(
      xb, wgub, counts, offsets, ids, GU);
  swiglu_cvt_kernel<<<10240, 256, 0, stream>>>(GU, wd, wdb);
  gemm2_kernel<<<dim3(16, N_TOK / 128, N_EXP), 256, 0, stream>>>(
      GU, wdb, counts, offsets, ids, wts, out);
}

// Round 7
// 412.838 us; speedup vs baseline: 1.2323x; 1.0908x over previous
//
#include <hip/hip_runtime.h>
#include <cstdint>

// ---- problem constants (MoEFeedForward: N=4096, D=1024, F=2048, E=8, top-2) ----
#define N_TOK 4096
#define D_MODEL 1024
#define D_FF 2048
#define D_GU 4096          // 2*D_FF: gate_up col space; also GU row pitch
#define N_EXP 8

typedef __bf16 bf16;
typedef __bf16 bf16x8 __attribute__((ext_vector_type(8)));
typedef float f32x4 __attribute__((ext_vector_type(4)));

typedef __attribute__((address_space(1))) void v1_t;
typedef __attribute__((address_space(3))) void v3_t;

// async global->LDS raw copy, 16B/lane; dest = wave-uniform base + lane*16
__device__ __forceinline__ void cp16(void* lds, const void* g) {
  __builtin_amdgcn_global_load_lds((v1_t*)g, (v3_t*)lds, 16, 0, 0);
}

__device__ __forceinline__ f32x4 mfma16(bf16x8 a, bf16x8 b, f32x4 c) {
  return __builtin_amdgcn_mfma_f32_16x16x32_bf16(a, b, c, 0, 0, 0);
}

__device__ __forceinline__ bf16x8 cvt8(float4 a, float4 b) {
  bf16x8 v;
  v[0] = (bf16)a.x; v[1] = (bf16)a.y; v[2] = (bf16)a.z; v[3] = (bf16)a.w;
  v[4] = (bf16)b.x; v[5] = (bf16)b.y; v[6] = (bf16)b.z; v[7] = (bf16)b.w;
  return v;
}

// ======== router + wgu-cvt fused launch ========
// Also emits tinfo[token] = (e0, pos0, e1, pos1) for the atomic-free combine.
__global__ __launch_bounds__(256) void router_cvt_kernel(
    const float* __restrict__ x, const float* __restrict__ wr,
    int* __restrict__ counts, int* __restrict__ ids, float* __restrict__ wts,
    int4* __restrict__ tinfo,
    bf16* __restrict__ xb, const float* __restrict__ wgu, bf16* __restrict__ wgub)
{
  if (blockIdx.x >= 128) {
    const int n8 = (N_EXP * D_GU * D_MODEL) / 8;
    int i = (blockIdx.x - 128) * 256 + threadIdx.x;
    const int stride = (gridDim.x - 128) * 256;
    for (; i < n8; i += stride) {
      const float4* s = (const float4*)wgu + 2 * (size_t)i;
      ((bf16x8*)wgub)[i] = cvt8(s[0], s[1]);
    }
    return;
  }

  __shared__ int lcnt[N_EXP];
  __shared__ int gbase[N_EXP];
  __shared__ int s_e0[32], s_l0[32], s_e1[32], s_l1[32];
  __shared__ float s_p0[32], s_p1[32];

  const int tid  = threadIdx.x;
  const int wave = tid >> 6;
  const int lane = tid & 63;
  if (tid < N_EXP) lcnt[tid] = 0;
  __syncthreads();

  for (int it = 0; it < 8; ++it) {
    const int li = it * 4 + wave;                 // local token 0..31
    const int token = blockIdx.x * 32 + li;

    const float4* xrow = (const float4*)(x + (size_t)token * D_MODEL + lane * 16);
    float4 x0 = xrow[0], x1 = xrow[1], x2 = xrow[2], x3 = xrow[3];

    bf16* xd = xb + (size_t)token * D_MODEL + lane * 16;
    *(bf16x8*)xd       = cvt8(x0, x1);
    *(bf16x8*)(xd + 8) = cvt8(x2, x3);

    float logit[N_EXP];
#pragma unroll
    for (int e = 0; e < N_EXP; ++e) {
      const float4* wrow = (const float4*)(wr + e * D_MODEL + lane * 16);
      float4 w0 = wrow[0], w1 = wrow[1], w2 = wrow[2], w3 = wrow[3];
      float s = x0.x*w0.x + x0.y*w0.y + x0.z*w0.z + x0.w*w0.w
              + x1.x*w1.x + x1.y*w1.y + x1.z*w1.z + x1.w*w1.w
              + x2.x*w2.x + x2.y*w2.y + x2.z*w2.z + x2.w*w2.w
              + x3.x*w3.x + x3.y*w3.y + x3.z*w3.z + x3.w*w3.w;
#pragma unroll
      for (int m = 32; m >= 1; m >>= 1) s += __shfl_xor(s, m);
      logit[e] = fminf(fmaxf(s, -1e4f), 1e4f);    // reference CLAMP
    }

    if (lane == 0) {
      float mx = logit[0];
#pragma unroll
      for (int e = 1; e < N_EXP; ++e) mx = fmaxf(mx, logit[e]);
      float ex[N_EXP], sum = 0.f;
#pragma unroll
      for (int e = 0; e < N_EXP; ++e) { ex[e] = expf(logit[e] - mx); sum += ex[e]; }
      float p[N_EXP];
#pragma unroll
      for (int e = 0; e < N_EXP; ++e)
        p[e] = fminf(fmaxf(ex[e] / (sum + 1e-8f), 1e-8f), 1.0f);
      int e0 = 0;
#pragma unroll
      for (int e = 1; e < N_EXP; ++e) if (p[e] > p[e0]) e0 = e;
      int e1 = (e0 == 0) ? 1 : 0;
#pragma unroll
      for (int e = 0; e < N_EXP; ++e) if (e != e0 && p[e] > p[e1]) e1 = e;
      float p0 = p[e0], p1 = p[e1];
      float inv = 1.f / (p0 + p1 + 1e-8f);
      s_e0[li] = e0; s_l0[li] = atomicAdd(&lcnt[e0], 1); s_p0[li] = p0 * inv;
      s_e1[li] = e1; s_l1[li] = atomicAdd(&lcnt[e1], 1); s_p1[li] = p1 * inv;
    }
  }
  __syncthreads();
  if (tid < N_EXP) gbase[tid] = atomicAdd(&counts[tid], lcnt[tid]);
  __syncthreads();
  if (tid < 32) {
    const int token = blockIdx.x * 32 + tid;
    int e0 = s_e0[tid], e1 = s_e1[tid];
    int a = gbase[e0] + s_l0[tid];
    int b = gbase[e1] + s_l1[tid];
    ids[e0 * N_TOK + a] = token; wts[e0 * N_TOK + a] = s_p0[tid];
    ids[e1 * N_TOK + b] = token; wts[e1 * N_TOK + b] = s_p1[tid];
    tinfo[token] = make_int4(e0, a, e1, b);       // for combine gather
  }
}

__global__ void offsets_kernel(const int* __restrict__ counts, int* __restrict__ offsets) {
  if (threadIdx.x == 0) {
    int r = 0;
#pragma unroll
    for (int e = 0; e < N_EXP; ++e) { offsets[e] = r; r += counts[e]; }
  }
}

// ====== GEMM1a: gathered xb @ Wgu_b^T -> GU bf16 (compacted rows, pitch 4096) ======
// 128x128 tile, BK=64, swizzled LDS (0 bank conflicts, round-6 verified).
// 1D grid + XCD-chunked decode: all 32 col-tiles sharing one A-panel stay on one XCD.
__global__ __launch_bounds__(256, 2) void gemm1a_kernel(
    const bf16* __restrict__ xb, const bf16* __restrict__ wgu,
    const int* __restrict__ counts, const int* __restrict__ offsets,
    const int* __restrict__ ids, bf16* __restrict__ GU)
{
  // nwg = 8192; dispatch-order XCD heuristic: xcd = bid&7 gets logical chunk of 1024
  const int bid = blockIdx.x;
  const int l   = (bid & 7) * 1024 + (bid >> 3);
  const int cx  = l & 31;                       // col tile 0..31
  const int g   = l >> 5;
  const int by  = g & 31;                       // row tile 0..31
  const int e   = g >> 5;                       // expert 0..7

  const int cnt = counts[e];
  const int row0 = by * 128;
  if (row0 >= cnt) return;
  const int c0 = cx * 128;                      // gate_up col tile in [0, 4096)

  __shared__ bf16 lA[128 * 64];
  __shared__ bf16 lB[128 * 64];

  const int tid  = threadIdx.x;
  const int lane = tid & 63;
  const int w    = tid >> 6;                        // wave 0..3
  const int l8   = lane >> 3;                       // row-within-pass 0..7
  const int ssrc = ((lane & 7) ^ l8) * 8;           // inverse-swizzled k-elem offset

  const int* ide = ids + e * N_TOK;
  const bf16* wge = wgu + (size_t)e * D_GU * D_MODEL;
  const bf16* srcA[4];
  const bf16* srcB[4];
#pragma unroll
  for (int p = 0; p < 4; ++p) {
    const int r = w * 32 + p * 8 + l8;              // LDS tile row 0..127
    srcA[p] = xb  + (size_t)ide[min(row0 + r, cnt - 1)] * D_MODEL + ssrc;
    srcB[p] = wge + (size_t)(c0 + r) * D_MODEL + ssrc;
  }
  char* const dA = (char*)lA + w * 4096;            // + p*1024; dest = base + lane*16
  char* const dB = (char*)lB + w * 4096;

  const int wm = w >> 1;
  const int wn = w & 1;
  const int fr = lane & 15;
  const int fq = lane >> 4;
  const char* pAr = (const char*)lA + (wm * 64 + fr) * 128;   // + fm*2048 + ko
  const char* pBr = (const char*)lB + (wn * 64 + fr) * 128;   // + fn*2048 + ko
  const int ko0 = (fq << 4) ^ ((fr & 7) << 4);                // kk=0 swizzled k-offset
  const int ko1 = (64 + (fq << 4)) ^ ((fr & 7) << 4);         // kk=1

  f32x4 acc[4][4];
#pragma unroll
  for (int i = 0; i < 4; ++i)
#pragma unroll
    for (int j = 0; j < 4; ++j)
#pragma unroll
      for (int k = 0; k < 4; ++k) acc[i][j][k] = 0.f;

  for (int kt = 0; kt < D_MODEL / 64; ++kt) {
#pragma unroll
    for (int p = 0; p < 4; ++p) cp16(dA + p * 1024, srcA[p]);
#pragma unroll
    for (int p = 0; p < 4; ++p) cp16(dB + p * 1024, srcB[p]);
#pragma unroll
    for (int p = 0; p < 4; ++p) { srcA[p] += 64; srcB[p] += 64; }
    __syncthreads();
    {
      bf16x8 a[4];
#pragma unroll
      for (int fm = 0; fm < 4; ++fm) a[fm] = *(const bf16x8*)(pAr + fm * 2048 + ko0);
#pragma unroll
      for (int fn = 0; fn < 4; ++fn) {
        bf16x8 b = *(const bf16x8*)(pBr + fn * 2048 + ko0);
#pragma unroll
        for (int fm = 0; fm < 4; ++fm) acc[fm][fn] = mfma16(a[fm], b, acc[fm][fn]);
      }
#pragma unroll
      for (int fm = 0; fm < 4; ++fm) a[fm] = *(const bf16x8*)(pAr + fm * 2048 + ko1);
#pragma unroll
      for (int fn = 0; fn < 4; ++fn) {
        bf16x8 b = *(const bf16x8*)(pBr + fn * 2048 + ko1);
#pragma unroll
        for (int fm = 0; fm < 4; ++fm) acc[fm][fn] = mfma16(a[fm], b, acc[fm][fn]);
      }
    }
    __syncthreads();
  }

  const int hbase = offsets[e] + row0;
#pragma unroll
  for (int fm = 0; fm < 4; ++fm) {
#pragma unroll
    for (int fn = 0; fn < 4; ++fn) {
#pragma unroll
      for (int i = 0; i < 4; ++i) {
        int m = wm * 64 + fm * 16 + fq * 4 + i;   // C/D: row = quad*4+reg
        if (row0 + m < cnt) {
          int col = c0 + wn * 64 + fn * 16 + fr;  // C/D: col = lane&15
          GU[(size_t)(hbase + m) * D_GU + col] = (bf16)acc[fm][fn][i];
        }
      }
    }
  }
}

// ====== SwiGLU in-place + wd-cvt fused launch ======
__global__ __launch_bounds__(256) void swiglu_cvt_kernel(
    bf16* __restrict__ GU, const float* __restrict__ wd, bf16* __restrict__ wdb)
{
  if (blockIdx.x >= 8192) {
    const int n8 = (N_EXP * D_MODEL * D_FF) / 8;
    int i = (blockIdx.x - 8192) * 256 + threadIdx.x;
    const int stride = (gridDim.x - 8192) * 256;
    for (; i < n8; i += stride) {
      const float4* s = (const float4*)wd + 2 * (size_t)i;
      ((bf16x8*)wdb)[i] = cvt8(s[0], s[1]);
    }
    return;
  }
  const int idx = blockIdx.x * 256 + threadIdx.x;
  const int row = idx >> 8;
  const int col = (idx & 255) * 8;
  bf16* g = GU + (size_t)row * D_GU + col;
  bf16x8 g8 = *(const bf16x8*)g;
  bf16x8 u8 = *(const bf16x8*)(g + D_FF);
  bf16x8 h;
#pragma unroll
  for (int j = 0; j < 8; ++j) {
    float u = (float)u8[j];
    float gg = (float)g8[j];
    h[j] = (bf16)(gg * u / (1.f + expf(-u)));
  }
  *(bf16x8*)g = h;
}

// ====== GEMM2: H(=GU gate half, pitch 4096) @ Wd_b^T -> weighted fp32 rows in O ======
// No atomics: O[compacted_row][0..1024) = wts[row] * acc, coalesced f32 stores.
// BK=64, swizzled LDS. 1D grid + XCD-chunked decode: each XCD handles exactly one
// expert (w_down_e = 4 MB fits its L2) and all col-tiles sharing an A-panel.
__global__ __launch_bounds__(256, 2) void gemm2_kernel(
    const bf16* __restrict__ GU, const bf16* __restrict__ wdb,
    const int* __restrict__ counts, const int* __restrict__ offsets,
    const float* __restrict__ wts, float* __restrict__ O)
{
  // nwg = 2048; logical l = xcd*256 + serial; x-fastest: cx(8), by(32), e(8)
  const int bid = blockIdx.x;
  const int l   = (bid & 7) * 256 + (bid >> 3);
  const int cx  = l & 7;                        // col tile 0..7
  const int g   = l >> 3;
  const int by  = g & 31;                       // row tile 0..31
  const int e   = g >> 5;                       // expert 0..7 (== xcd by construction)

  const int cnt = counts[e];
  const int row0 = by * 128;
  if (row0 >= cnt) return;
  const int c0 = cx * 128;                      // output col tile in [0, 1024)
  const int base = offsets[e];

  __shared__ bf16 lA[128 * 64];
  __shared__ bf16 lB[128 * 64];

  const int tid  = threadIdx.x;
  const int lane = tid & 63;
  const int w    = tid >> 6;
  const int l8   = lane >> 3;
  const int ssrc = ((lane & 7) ^ l8) * 8;

  const bf16* wde = wdb + (size_t)e * D_MODEL * D_FF;
  const bf16* srcA[4];
  const bf16* srcB[4];
#pragma unroll
  for (int p = 0; p < 4; ++p) {
    const int r = w * 32 + p * 8 + l8;
    srcA[p] = GU  + (size_t)(base + min(row0 + r, cnt - 1)) * D_GU + ssrc;
    srcB[p] = wde + (size_t)(c0 + r) * D_FF + ssrc;
  }
  char* const dA = (char*)lA + w * 4096;
  char* const dB = (char*)lB + w * 4096;

  const int wm = w >> 1;
  const int wn = w & 1;
  const int fr = lane & 15;
  const int fq = lane >> 4;
  const char* pAr = (const char*)lA + (wm * 64 + fr) * 128;
  const char* pBr = (const char*)lB + (wn * 64 + fr) * 128;
  const int ko0 = (fq << 4) ^ ((fr & 7) << 4);
  const int ko1 = (64 + (fq << 4)) ^ ((fr & 7) << 4);

  f32x4 acc[4][4];
#pragma unroll
  for (int i = 0; i < 4; ++i)
#pragma unroll
    for (int j = 0; j < 4; ++j)
#pragma unroll
      for (int k = 0; k < 4; ++k) acc[i][j][k] = 0.f;

  for (int kt = 0; kt < D_FF / 64; ++kt) {      // 32 K-steps (gate half cols [0,2048))
#pragma unroll
    for (int p = 0; p < 4; ++p) cp16(dA + p * 1024, srcA[p]);
#pragma unroll
    for (int p = 0; p < 4; ++p) cp16(dB + p * 1024, srcB[p]);
#pragma unroll
    for (int p = 0; p < 4; ++p) { srcA[p] += 64; srcB[p] += 64; }
    __syncthreads();
    {
      bf16x8 a[4];
#pragma unroll
      for (int fm = 0; fm < 4; ++fm) a[fm] = *(const bf16x8*)(pAr + fm * 2048 + ko0);
#pragma unroll
      for (int fn = 0; fn < 4; ++fn) {
        bf16x8 b = *(const bf16x8*)(pBr + fn * 2048 + ko0);
#pragma unroll
        for (int fm = 0; fm < 4; ++fm) acc[fm][fn] = mfma16(a[fm], b, acc[fm][fn]);
      }
#pragma unroll
      for (int fm = 0; fm < 4; ++fm) a[fm] = *(const bf16x8*)(pAr + fm * 2048 + ko1);
#pragma unroll
      for (int fn = 0; fn < 4; ++fn) {
        bf16x8 b = *(const bf16x8*)(pBr + fn * 2048 + ko1);
#pragma unroll
        for (int fm = 0; fm < 4; ++fm) acc[fm][fn] = mfma16(a[fm], b, acc[fm][fn]);
      }
    }
    __syncthreads();
  }

  const float* wte = wts + e * N_TOK;
#pragma unroll
  for (int fm = 0; fm < 4; ++fm) {
#pragma unroll
    for (int i = 0; i < 4; ++i) {
      int m = wm * 64 + fm * 16 + fq * 4 + i;
      if (row0 + m < cnt) {
        float wgt = wte[row0 + m];
        float* orow = O + (size_t)(base + row0 + m) * D_MODEL;
#pragma unroll
        for (int fn = 0; fn < 4; ++fn) {
          int col = c0 + wn * 64 + fn * 16 + fr;
          orow[col] = wgt * acc[fm][fn][i];     // coalesced, single writer
        }
      }
    }
  }
}

// ====== combine: out[t] = O[off[e0]+p0] + O[off[e1]+p1] (fully overwrites out) ======
__global__ __launch_bounds__(256) void combine_kernel(
    const float* __restrict__ O, const int* __restrict__ offsets,
    const int4* __restrict__ tinfo, float* __restrict__ out)
{
  const int t = blockIdx.x;
  const int4 ti = tinfo[t];
  const float4* r0 = (const float4*)(O + (size_t)(offsets[ti.x] + ti.y) * D_MODEL);
  const float4* r1 = (const float4*)(O + (size_t)(offsets[ti.z] + ti.w) * D_MODEL);
  float4 a = r0[threadIdx.x];
  float4 b = r1[threadIdx.x];
  float4 s; s.x = a.x + b.x; s.y = a.y + b.y; s.z = a.z + b.z; s.w = a.w + b.w;
  ((float4*)(out + (size_t)t * D_MODEL))[threadIdx.x] = s;
}

// =========================================================================================
extern "C" void kernel_launch(void* const* d_in, const int* in_sizes, int n_in,
                              void* d_out, int out_size, void* d_ws, size_t ws_size,
                              hipStream_t stream) {
  const float* x   = (const float*)d_in[0];
  const float* wr  = (const float*)d_in[1];
  const float* wgu = (const float*)d_in[2];
  const float* wd  = (const float*)d_in[3];
  float* out = (float*)d_out;

  char* ws = (char*)d_ws;
  int*   counts  = (int*)ws;                             // 32 B
  int*   offsets = (int*)(ws + 64);                      // 32 B
  int*   ids     = (int*)(ws + 4096);                    // 128 KB
  float* wts     = (float*)(ws + 4096 + 131072);         // 128 KB
  int4*  tinfo   = (int4*)(ws + 4096 + 262144);          // 64 KB (ends < 524288)
  bf16*  xb      = (bf16*)(ws + 524288);                 // 8 MB
  bf16*  wgub    = (bf16*)(ws + 524288 + 8388608);       // 64 MB
  bf16*  wdb     = wgub;                                 // lower 32 MB alias (post-gemm1a)
  float* O       = (float*)(ws + 524288 + 8388608 + 33554432); // upper 32 MB of wgub region
  bf16*  GU      = (bf16*)(ws + 524288 + 8388608 + 67108864);  // 8192 x 4096 bf16 = 64 MB

  hipMemsetAsync(counts, 0, 64, stream);
  router_cvt_kernel<<<2048, 256, 0, stream>>>(x, wr, counts, ids, wts, tinfo, xb, wgu, wgub);
  offsets_kernel<<<1, 64, 0, stream>>>(counts, offsets);
  gemm1a_kernel<<<8192, 256, 0, stream>>>(xb, wgub, counts, offsets, ids, GU);
  swiglu_cvt_kernel<<<10240, 256, 0, stream>>>(GU, wd, wdb);
  gemm2_kernel<<<2048, 256, 0, stream>>>(GU, wdb, counts, offsets, wts, O);
  combine_kernel<<<N_TOK, 256, 0, stream>>>(O, offsets, tinfo, out);
}